// Round 2
// baseline (450.984 us; speedup 1.0000x reference)
//
#include <hip/hip_runtime.h>

// ContinuousPool: 10x [cur += p*(maxpool3x3_same(cur)-cur)] then avgpool2x2.
// One block (256 thr) per (n,c) plane; thread tile = 8 rows x 8 cols.
// vs previous 512-thr/4x8 version: per-element LDS traffic and barrier count
// halved (2 halo rows per 8 owned rows), LDS 65.5KB -> 31.7KB so 4 blocks/CU
// resident = 4 independent barrier domains per SIMD (was 2) -> barrier/LDS
// latency per step is hidden by 3 other blocks' waves instead of 1.
// Horizontal 3-max halo via DPP row_shr/row_shl (tx == 16-lane DPP row-lane;
// out-of-row lanes receive old = -inf == reduce_window padding).
// Vertical halo: only hmax of tile boundary rows (top/bot) goes through LDS.
// Double-buffered LDS -> ONE barrier per timestep. LDS row stride 132 floats
// (528B = 16 mod 128) so ty-consecutive rows shift start banks by 4 ->
// b128 accesses cover all 8 aligned bank-quads (floor-optimal).

#define TSTEPS 10
#define PW 128
#define HP 132
#define HROWS 15   // 16 row-tiles -> 15 inter-tile boundaries

__device__ __forceinline__ float dpp_left(float x) {
    // row_shr:1 -> lane i gets lane i-1 within its 16-lane DPP row; row-lane 0 -> old(-inf)
    int r = __builtin_amdgcn_update_dpp((int)0xff800000, __float_as_int(x),
                                        0x111, 0xf, 0xf, false);
    return __int_as_float(r);
}
__device__ __forceinline__ float dpp_right(float x) {
    // row_shl:1 -> lane i gets lane i+1; row-lane 15 -> old(-inf)
    int r = __builtin_amdgcn_update_dpp((int)0xff800000, __float_as_int(x),
                                        0x101, 0xf, 0xf, false);
    return __int_as_float(r);
}

__device__ __forceinline__ float max3f(float a, float b, float c) {
    return fmaxf(fmaxf(a, b), c);   // folds to v_max3_f32
}

// h[c] = max(v[c-1], v[c], v[c+1]) over the thread's 8-wide row, halo via DPP.
__device__ __forceinline__ void hmax_row(const float* v, float* h) {
    float vl = dpp_left(v[7]);   // left neighbor thread's rightmost col
    float vr = dpp_right(v[0]);  // right neighbor thread's leftmost col
    h[0] = max3f(vl, v[0], v[1]);
#pragma unroll
    for (int c = 1; c < 7; ++c) h[c] = max3f(v[c - 1], v[c], v[c + 1]);
    h[7] = max3f(v[6], v[7], vr);
}

__device__ __forceinline__ void ld8(const float* a, float* d) {
    float4 u = ((const float4*)a)[0], v = ((const float4*)a)[1];
    d[0] = u.x; d[1] = u.y; d[2] = u.z; d[3] = u.w;
    d[4] = v.x; d[5] = v.y; d[6] = v.z; d[7] = v.w;
}
__device__ __forceinline__ void st8(float* a, const float* d) {
    ((float4*)a)[0] = make_float4(d[0], d[1], d[2], d[3]);
    ((float4*)a)[1] = make_float4(d[4], d[5], d[6], d[7]);
}

// One timestep. topBuf[i] holds hTop of tile (i+1); botBuf[i] holds hBot of tile i.
__device__ __forceinline__ void do_step(float cur[8][8], float p, int tx, int ty,
                                        float* __restrict__ topBuf,
                                        float* __restrict__ botBuf) {
    const float NEG = -__builtin_huge_valf();
    const int x0 = tx * 8;

    float hTop[8], hBot[8];
    hmax_row(cur[0], hTop);
    hmax_row(cur[7], hBot);

    if (ty > 0)     st8(topBuf + (ty - 1) * HP + x0, hTop);
    if (ty < HROWS) st8(botBuf + ty * HP + x0, hBot);

    __syncthreads();

    float hm[8], hnx[8];
    if (ty > 0) {
        ld8(botBuf + (ty - 1) * HP + x0, hm);      // hBot of tile ty-1
    } else {
#pragma unroll
        for (int c = 0; c < 8; ++c) hm[c] = NEG;
    }
    if (ty < HROWS) {
        ld8(topBuf + ty * HP + x0, hnx);           // hTop of tile ty+1
    } else {
#pragma unroll
        for (int c = 0; c < 8; ++c) hnx[c] = NEG;
    }

    // rolling vertical 3-max + lerp; h-window rows: hm, hc, hn
    float hc[8];
#pragma unroll
    for (int c = 0; c < 8; ++c) hc[c] = hTop[c];   // hTop dead after this (aliases hc)

#pragma unroll
    for (int r = 0; r < 8; ++r) {
        float hn[8];
        if (r < 6) {
            hmax_row(cur[r + 1], hn);              // cur[r+1] still pre-update
        } else if (r == 6) {
#pragma unroll
            for (int c = 0; c < 8; ++c) hn[c] = hBot[c];
        } else {
#pragma unroll
            for (int c = 0; c < 8; ++c) hn[c] = hnx[c];
        }
#pragma unroll
        for (int c = 0; c < 8; ++c) {
            float v = max3f(hm[c], hc[c], hn[c]);
            cur[r][c] = fmaf(p, v - cur[r][c], cur[r][c]);
        }
#pragma unroll
        for (int c = 0; c < 8; ++c) { hm[c] = hc[c]; hc[c] = hn[c]; }
    }
    // no trailing barrier: next step uses the other LDS buffer; re-use of this
    // buffer happens after the NEXT step's barrier, by which time all waves'
    // reads here have completed (data consumed before that barrier).
}

__global__ __launch_bounds__(256, 4)
void cpool_kernel(const float* __restrict__ x, const float* __restrict__ ps,
                  float* __restrict__ out) {
    __shared__ float lds[2][2][HROWS * HP];   // 2*2*1980 floats = 31,680 B

    const int b = blockIdx.x;                 // plane id = n*96 + c
    const float p = ps[b % 96];

    const int tx = threadIdx.x & 15;          // DPP row-lane
    const int ty = threadIdx.x >> 4;          // 0..15, 8 rows each
    const int x0 = tx * 8;
    const int y0 = ty * 8;

    const float* __restrict__ xp = x + (size_t)b * (PW * PW);

    float cur[8][8];
#pragma unroll
    for (int r = 0; r < 8; ++r) ld8(xp + (y0 + r) * PW + x0, cur[r]);

#pragma unroll 1
    for (int tt = 0; tt < TSTEPS / 2; ++tt) {
        do_step(cur, p, tx, ty, lds[0][0], lds[0][1]);
        do_step(cur, p, tx, ty, lds[1][0], lds[1][1]);
    }

    // epilogue: 2x2 avg pool -> 4 rows x 4 cols per thread
    float* __restrict__ op = out + (size_t)b * (64 * 64);
#pragma unroll
    for (int r2 = 0; r2 < 4; ++r2) {
        float4 o;
        o.x = 0.25f * (cur[2*r2][0] + cur[2*r2][1] + cur[2*r2+1][0] + cur[2*r2+1][1]);
        o.y = 0.25f * (cur[2*r2][2] + cur[2*r2][3] + cur[2*r2+1][2] + cur[2*r2+1][3]);
        o.z = 0.25f * (cur[2*r2][4] + cur[2*r2][5] + cur[2*r2+1][4] + cur[2*r2+1][5]);
        o.w = 0.25f * (cur[2*r2][6] + cur[2*r2][7] + cur[2*r2+1][6] + cur[2*r2+1][7]);
        *(float4*)(op + (size_t)((4 * ty + r2) * 64 + tx * 4)) = o;
    }
}

extern "C" void kernel_launch(void* const* d_in, const int* in_sizes, int n_in,
                              void* d_out, int out_size, void* d_ws, size_t ws_size,
                              hipStream_t stream) {
    const float* x  = (const float*)d_in[0];   // (32,96,128,128) fp32
    const float* ps = (const float*)d_in[1];   // (1,96,1,1) fp32
    float* out = (float*)d_out;                // (32,96,64,64) fp32
    (void)in_sizes; (void)n_in; (void)out_size; (void)d_ws; (void)ws_size;

    cpool_kernel<<<dim3(32 * 96), dim3(256), 0, stream>>>(x, ps, out);
}

// Round 3
// 290.999 us; speedup vs baseline: 1.5498x; 1.5498x over previous
//
#include <hip/hip_runtime.h>

// ContinuousPool: 10x [cur += p*(maxpool3x3_same(cur)-cur)] then avgpool2x2.
// One block (512 thr) per (n,c) plane; thread tile = 4 rows x 8 cols.
// (Reverted from 8x8/256thr: that variant needed ~120 live VGPRs, allocator
// collapsed to 64 and spilled ~20 floats/thread/step to scratch -> +607 MB
// HBM writes, 2.3x slower. 4x8 peaks at ~90 live regs, no spills.)
// Horizontal 3-max halo via DPP row_shr/row_shl (tx == 16-lane DPP row-lane;
// out-of-row lanes receive old = -inf == reduce_window padding).
// Vertical halo: only hmax of tile boundary rows (top/bot) goes through LDS.
// Double-buffered LDS -> ONE barrier per timestep. LDS row stride 132 floats
// (528B = 16 mod 128) so ty-consecutive rows shift start banks by 4 ->
// b128 accesses cover all 8 aligned bank-quads (floor-optimal).
// THIS ROUND: explicit ILP schedule in do_step — after the barrier, issue the
// two halo ld8s, then compute rows 1,2 (pure register/DPP work, ~140 cy) which
// need no LDS data, then the LDS-dependent rows 0,3. Hides the ~120cy LDS
// latency under independent VALU instead of stalling at r=0 as the old
// rolling-window (hm/hc/hn) order did.

#define TSTEPS 10
#define PW 128
#define HP 132
#define HROWS 31   // 32 row-tiles -> 31 inter-tile boundaries

__device__ __forceinline__ float dpp_left(float x) {
    // row_shr:1 -> lane i gets lane i-1 within its 16-lane DPP row; row-lane 0 -> old(-inf)
    int r = __builtin_amdgcn_update_dpp((int)0xff800000, __float_as_int(x),
                                        0x111, 0xf, 0xf, false);
    return __int_as_float(r);
}
__device__ __forceinline__ float dpp_right(float x) {
    // row_shl:1 -> lane i gets lane i+1; row-lane 15 -> old(-inf)
    int r = __builtin_amdgcn_update_dpp((int)0xff800000, __float_as_int(x),
                                        0x101, 0xf, 0xf, false);
    return __int_as_float(r);
}

__device__ __forceinline__ float max3f(float a, float b, float c) {
    return fmaxf(fmaxf(a, b), c);   // folds to v_max3_f32
}

// h[c] = max(v[c-1], v[c], v[c+1]) over the thread's 8-wide row, halo via DPP.
__device__ __forceinline__ void hmax_row(const float* v, float* h) {
    float vl = dpp_left(v[7]);   // left neighbor thread's rightmost col
    float vr = dpp_right(v[0]);  // right neighbor thread's leftmost col
    h[0] = max3f(vl, v[0], v[1]);
#pragma unroll
    for (int c = 1; c < 7; ++c) h[c] = max3f(v[c - 1], v[c], v[c + 1]);
    h[7] = max3f(v[6], v[7], vr);
}

__device__ __forceinline__ void ld8(const float* a, float* d) {
    float4 u = ((const float4*)a)[0], v = ((const float4*)a)[1];
    d[0] = u.x; d[1] = u.y; d[2] = u.z; d[3] = u.w;
    d[4] = v.x; d[5] = v.y; d[6] = v.z; d[7] = v.w;
}
__device__ __forceinline__ void st8(float* a, const float* d) {
    ((float4*)a)[0] = make_float4(d[0], d[1], d[2], d[3]);
    ((float4*)a)[1] = make_float4(d[4], d[5], d[6], d[7]);
}

// One timestep. topBuf[i] holds hTop of tile (i+1); botBuf[i] holds hBot of tile i.
__device__ __forceinline__ void do_step(float cur[4][8], float p, int tx, int ty,
                                        float* __restrict__ topBuf,
                                        float* __restrict__ botBuf) {
    const float NEG = -__builtin_huge_valf();
    const int x0 = tx * 8;

    // boundary hmax rows, store to LDS first
    float h0[8], h3[8];
    hmax_row(cur[0], h0);
    hmax_row(cur[3], h3);
    if (ty > 0)     st8(topBuf + (ty - 1) * HP + x0, h0);
    if (ty < HROWS) st8(botBuf + ty * HP + x0, h3);

    __syncthreads();

    // issue halo loads (in flight while rows 1,2 are processed)
    float hm[8], hnx[8];
    if (ty > 0) {
        ld8(botBuf + (ty - 1) * HP + x0, hm);      // hBot of tile ty-1
    } else {
#pragma unroll
        for (int c = 0; c < 8; ++c) hm[c] = NEG;
    }
    if (ty < HROWS) {
        ld8(topBuf + ty * HP + x0, hnx);           // hTop of tile ty+1
    } else {
#pragma unroll
        for (int c = 0; c < 8; ++c) hnx[c] = NEG;
    }

    // LDS-independent work: interior hmax + rows 1,2 updates (register-only)
    float h1[8], h2[8];
    hmax_row(cur[1], h1);
    hmax_row(cur[2], h2);
#pragma unroll
    for (int c = 0; c < 8; ++c) {
        float v = max3f(h0[c], h1[c], h2[c]);
        cur[1][c] = fmaf(p, v - cur[1][c], cur[1][c]);
    }
#pragma unroll
    for (int c = 0; c < 8; ++c) {
        float v = max3f(h1[c], h2[c], h3[c]);
        cur[2][c] = fmaf(p, v - cur[2][c], cur[2][c]);
    }

    // LDS-dependent rows last (loads have had ~140 cy of cover)
#pragma unroll
    for (int c = 0; c < 8; ++c) {
        float v = max3f(hm[c], h0[c], h1[c]);
        cur[0][c] = fmaf(p, v - cur[0][c], cur[0][c]);
    }
#pragma unroll
    for (int c = 0; c < 8; ++c) {
        float v = max3f(h2[c], h3[c], hnx[c]);
        cur[3][c] = fmaf(p, v - cur[3][c], cur[3][c]);
    }
    // no trailing barrier: next step uses the other LDS buffer; re-use of this
    // buffer happens after the NEXT step's barrier, by which time all waves'
    // reads here have completed (data consumed before that barrier).
}

__global__ __launch_bounds__(512, 4)
void cpool_kernel(const float* __restrict__ x, const float* __restrict__ ps,
                  float* __restrict__ out) {
    __shared__ float lds[2][2][HROWS * HP];   // [buf][top=0/bot=1] : 65,472 B

    const int b = blockIdx.x;                 // plane id = n*96 + c
    const float p = ps[b % 96];

    const int tx = threadIdx.x & 15;          // DPP row-lane
    const int ty = threadIdx.x >> 4;          // 0..31, 4 rows each
    const int x0 = tx * 8;
    const int y0 = ty * 4;

    const float* __restrict__ xp = x + (size_t)b * (PW * PW);

    float cur[4][8];
#pragma unroll
    for (int r = 0; r < 4; ++r) ld8(xp + (y0 + r) * PW + x0, cur[r]);

#pragma unroll 1
    for (int tt = 0; tt < TSTEPS / 2; ++tt) {
        do_step(cur, p, tx, ty, lds[0][0], lds[0][1]);
        do_step(cur, p, tx, ty, lds[1][0], lds[1][1]);
    }

    // epilogue: 2x2 avg pool -> 2 rows x 4 cols per thread
    float* __restrict__ op = out + (size_t)b * (64 * 64);
#pragma unroll
    for (int r2 = 0; r2 < 2; ++r2) {
        float4 o;
        o.x = 0.25f * (cur[2*r2][0] + cur[2*r2][1] + cur[2*r2+1][0] + cur[2*r2+1][1]);
        o.y = 0.25f * (cur[2*r2][2] + cur[2*r2][3] + cur[2*r2+1][2] + cur[2*r2+1][3]);
        o.z = 0.25f * (cur[2*r2][4] + cur[2*r2][5] + cur[2*r2+1][4] + cur[2*r2+1][5]);
        o.w = 0.25f * (cur[2*r2][6] + cur[2*r2][7] + cur[2*r2+1][6] + cur[2*r2+1][7]);
        *(float4*)(op + (size_t)((2 * ty + r2) * 64 + tx * 4)) = o;
    }
}

extern "C" void kernel_launch(void* const* d_in, const int* in_sizes, int n_in,
                              void* d_out, int out_size, void* d_ws, size_t ws_size,
                              hipStream_t stream) {
    const float* x  = (const float*)d_in[0];   // (32,96,128,128) fp32
    const float* ps = (const float*)d_in[1];   // (1,96,1,1) fp32
    float* out = (float*)d_out;                // (32,96,64,64) fp32
    (void)in_sizes; (void)n_in; (void)out_size; (void)d_ws; (void)ws_size;

    cpool_kernel<<<dim3(32 * 96), dim3(512), 0, stream>>>(x, ps, out);
}